// Round 6
// baseline (332.433 us; speedup 1.0000x reference)
//
#include <hip/hip_runtime.h>
#include <math.h>

#define N_NODES 100000
#define N_EDGES 1600000
#define F 64          // IN_FEATS == HIDDEN == 64
#define NCLS 2

#define TM 64                                // nodes per node_mlp block
#define STRIDE 68                            // padded LDS row stride (floats)

// ---------------------------------------------------------------------------
// K1: h = feat @ W_in + b_in (registers only — never materialized!), then
// all four per-node linear projections:
//   A[n]   = h[n]·W_u        (src side of gate)
//   B[n]   = h[n]·W_v        (dst side of gate)
//   hw0[n] = h[n]·W_out[:,0] (pre-projected output, class 0)
//   hw1[n] = h[n]·W_out[:,1] (pre-projected output, class 1)
// nodeT[n] = (A, hw0, hw1, B) float4; Bv[n] = B (for 4B dst-side loads).
// Register-tiled fp32 GEMM, 64x64 tile, 4x4 micro-tile per thread.
// ---------------------------------------------------------------------------
__global__ __launch_bounds__(256) void node_mlp_kernel(
    const float* __restrict__ feat,
    const float* __restrict__ W_in,
    const float* __restrict__ b_in,
    const float* __restrict__ W_edge,
    const float* __restrict__ W_out,
    float4* __restrict__ nodeT,
    float*  __restrict__ Bv)
{
    __shared__ float sT[F * STRIDE];   // feat^T tile: sT[k*STRIDE + node]
    __shared__ float sW[F * F];        // W_in row-major
    __shared__ float sWu[F];
    __shared__ float sWv[F];
    __shared__ float sW0[F];
    __shared__ float sW1[F];

    const int tid = threadIdx.x;
    const int tx  = tid & 15;          // col group: cols tx*4 .. tx*4+3
    const int ty  = tid >> 4;          // node group: nodes ty*4 .. ty*4+3
    const int n0  = blockIdx.x * TM;

    for (int i = tid; i < F * F; i += 256) sW[i] = W_in[i];
    if (tid < F) {
        sWu[tid] = W_edge[tid];
        sWv[tid] = W_edge[F + tid];
        sW0[tid] = W_out[tid * NCLS + 0];
        sW1[tid] = W_out[tid * NCLS + 1];
    }

    // stage feat transposed
    #pragma unroll
    for (int p = 0; p < 4; ++p) {
        const int node = p * 16 + ty;
        const int k4   = tx * 4;
        const int n    = n0 + node;
        float4 v = make_float4(0.f, 0.f, 0.f, 0.f);
        if (n < N_NODES) v = *(const float4*)&feat[(size_t)n * F + k4];
        sT[(k4 + 0) * STRIDE + node] = v.x;
        sT[(k4 + 1) * STRIDE + node] = v.y;
        sT[(k4 + 2) * STRIDE + node] = v.z;
        sT[(k4 + 3) * STRIDE + node] = v.w;
    }
    __syncthreads();

    const float4 bb = *(const float4*)&b_in[tx * 4];
    float acc[4][4];
    #pragma unroll
    for (int i = 0; i < 4; ++i) {
        acc[i][0] = bb.x; acc[i][1] = bb.y; acc[i][2] = bb.z; acc[i][3] = bb.w;
    }

    #pragma unroll 4
    for (int k = 0; k < F; ++k) {
        const float4 a = *(const float4*)&sT[k * STRIDE + ty * 4];
        const float4 b = *(const float4*)&sW[k * F + tx * 4];
        const float av_[4] = {a.x, a.y, a.z, a.w};
        const float bv_[4] = {b.x, b.y, b.z, b.w};
        #pragma unroll
        for (int i = 0; i < 4; ++i)
            #pragma unroll
            for (int j = 0; j < 4; ++j)
                acc[i][j] += av_[i] * bv_[j];
    }

    // four projections: partial dot over this thread's 4 cols, butterfly
    // over the 16 lanes (tx) that share the node row.
    const float wu[4] = { sWu[tx*4+0], sWu[tx*4+1], sWu[tx*4+2], sWu[tx*4+3] };
    const float wv[4] = { sWv[tx*4+0], sWv[tx*4+1], sWv[tx*4+2], sWv[tx*4+3] };
    const float w0[4] = { sW0[tx*4+0], sW0[tx*4+1], sW0[tx*4+2], sW0[tx*4+3] };
    const float w1[4] = { sW1[tx*4+0], sW1[tx*4+1], sW1[tx*4+2], sW1[tx*4+3] };

    #pragma unroll
    for (int i = 0; i < 4; ++i) {
        const int n = n0 + ty * 4 + i;
        float pa = 0.f, pb = 0.f, p0 = 0.f, p1 = 0.f;
        #pragma unroll
        for (int j = 0; j < 4; ++j) {
            pa += acc[i][j] * wu[j];
            pb += acc[i][j] * wv[j];
            p0 += acc[i][j] * w0[j];
            p1 += acc[i][j] * w1[j];
        }
        #pragma unroll
        for (int off = 8; off > 0; off >>= 1) {
            pa += __shfl_xor(pa, off);
            pb += __shfl_xor(pb, off);
            p0 += __shfl_xor(p0, off);
            p1 += __shfl_xor(p1, off);
        }
        if (n < N_NODES && tx == 0) {
            nodeT[n] = make_float4(pa, p0, p1, pb);
            Bv[n]    = pb;
        }
    }
}

// ---------------------------------------------------------------------------
// K2: thread-per-edge. One 16B L2-resident gather (nodeT[src]), one 4B
// gather (Bv[dst]), sigmoid, then 2 fp32 atomicAdds into the 800 KB acc
// table + 1 int atomicAdd for degree. Footprint is L2-resident, so atomics
// don't generate HBM write-through.
// ---------------------------------------------------------------------------
__global__ __launch_bounds__(256) void edge_kernel(
    const int* __restrict__ src,
    const int* __restrict__ dst,
    const float4* __restrict__ nodeT,
    const float* __restrict__ Bv,
    const float* __restrict__ b_edge,
    float2* __restrict__ acc,
    int* __restrict__ deg)
{
    const int e = blockIdx.x * 256 + threadIdx.x;
    if (e >= N_EDGES) return;
    const int s = src[e];
    const int d = dst[e];
    const float4 t = nodeT[s];                 // (A, hw0, hw1, B)
    const float x = t.x + Bv[d] + b_edge[0];
    const float w = 1.0f / (1.0f + __expf(-x));
    atomicAdd(&acc[d].x, w * t.y);
    atomicAdd(&acc[d].y, w * t.z);
    atomicAdd(&deg[d], 1);
}

// ---------------------------------------------------------------------------
// K3: finalize — out[n] = (deg>0 ? acc[n] : (hw0,hw1)[n]) + b_out
// ---------------------------------------------------------------------------
__global__ __launch_bounds__(256) void finalize_kernel(
    const float2* __restrict__ acc,
    const int* __restrict__ deg,
    const float4* __restrict__ nodeT,
    const float* __restrict__ b_out,
    float2* __restrict__ out)
{
    const int n = blockIdx.x * 256 + threadIdx.x;
    if (n >= N_NODES) return;
    const float2 a = acc[n];
    const float4 t = nodeT[n];
    const int   dg = deg[n];
    const float o0 = (dg > 0 ? a.x : t.y) + b_out[0];
    const float o1 = (dg > 0 ? a.y : t.z) + b_out[1];
    out[n] = make_float2(o0, o1);
}

// ---------------------------------------------------------------------------
extern "C" void kernel_launch(void* const* d_in, const int* in_sizes, int n_in,
                              void* d_out, int out_size, void* d_ws, size_t ws_size,
                              hipStream_t stream) {
    const float* feat   = (const float*)d_in[0];
    const int*   src    = (const int*)d_in[1];
    const int*   dst    = (const int*)d_in[2];
    const float* W_in   = (const float*)d_in[3];
    const float* b_in   = (const float*)d_in[4];
    const float* W_edge = (const float*)d_in[5];
    const float* b_edge = (const float*)d_in[6];
    const float* W_out  = (const float*)d_in[7];
    const float* b_out  = (const float*)d_in[8];
    float2* out = (float2*)d_out;

    // workspace layout
    float4* nodeT = (float4*)d_ws;                           // N float4 (1.6 MB)
    float*  Bv    = (float*)(nodeT + N_NODES);               // N  (400 KB)
    float2* acc   = (float2*)(Bv + N_NODES);                 // N float2 (800 KB)
    int*    deg   = (int*)(acc + N_NODES);                   // N  (400 KB)

    hipMemsetAsync(acc, 0, (size_t)N_NODES * sizeof(float2), stream);
    hipMemsetAsync(deg, 0, (size_t)N_NODES * sizeof(int), stream);

    const int blocks_mlp   = (N_NODES + TM - 1) / TM;
    const int blocks_edges = (N_EDGES + 255) / 256;
    const int blocks_nodes = (N_NODES + 255) / 256;

    node_mlp_kernel<<<blocks_mlp, 256, 0, stream>>>(feat, W_in, b_in, W_edge, W_out,
                                                    nodeT, Bv);
    edge_kernel<<<blocks_edges, 256, 0, stream>>>(src, dst, nodeT, Bv, b_edge, acc, deg);
    finalize_kernel<<<blocks_nodes, 256, 0, stream>>>(acc, deg, nodeT, b_out, out);
}

// Round 7
// 185.793 us; speedup vs baseline: 1.7893x; 1.7893x over previous
//
#include <hip/hip_runtime.h>
#include <math.h>

#define N_NODES 100000
#define N_EDGES 1600000
#define F 64          // IN_FEATS == HIDDEN == 64
#define NCLS 2

#define BW_LOG 7
#define BW 128                               // nodes per bucket
#define NB ((N_NODES + BW - 1) / BW)         // 782 buckets
#define EPB (N_EDGES / 256)                  // 6250 edges per hist/scatter block

#define TM 64                                // nodes per node_mlp block
#define STRIDE 68                            // padded LDS row stride (floats)
#define BLOCKS_MLP ((N_NODES + TM - 1) / TM) // 1563

// ---------------------------------------------------------------------------
// K1 (fused): blocks [0, BLOCKS_MLP) run the node MLP + 4 projections;
// blocks [BLOCKS_MLP, BLOCKS_MLP+256) build the coarse dst-bucket histogram
// (aliasing the MLP's LDS). Projections per node n (h never materialized):
//   nodeT[n] = (A = h·W_u,  hw0 = h·W_out[:,0],  hw1 = h·W_out[:,1],  B = h·W_v)
// ---------------------------------------------------------------------------
__global__ __launch_bounds__(256) void mlp_hist_kernel(
    const float* __restrict__ feat,
    const float* __restrict__ W_in,
    const float* __restrict__ b_in,
    const float* __restrict__ W_edge,
    const float* __restrict__ W_out,
    const int*   __restrict__ dst,
    float4* __restrict__ nodeT,
    int*    __restrict__ bucket_cnt)
{
    __shared__ float sT[F * STRIDE];   // feat^T tile; hist blocks alias this
    __shared__ float sW[F * F];
    __shared__ float sWu[F];
    __shared__ float sWv[F];
    __shared__ float sW0[F];
    __shared__ float sW1[F];

    const int tid = threadIdx.x;

    // ---------------- histogram blocks ----------------
    if ((int)blockIdx.x >= BLOCKS_MLP) {
        int* hist = (int*)sT;                       // NB ints = 3.1 KB
        for (int i = tid; i < NB; i += 256) hist[i] = 0;
        __syncthreads();
        const int hb  = blockIdx.x - BLOCKS_MLP;
        const int beg = hb * EPB;
        const int end = beg + EPB;
        for (int e = beg + tid; e < end; e += 256)
            atomicAdd(&hist[dst[e] >> BW_LOG], 1);
        __syncthreads();
        for (int b = tid; b < NB; b += 256)
            if (hist[b]) atomicAdd(&bucket_cnt[b], hist[b]);
        return;
    }

    // ---------------- MLP blocks ----------------
    const int tx  = tid & 15;          // col group: cols tx*4 .. tx*4+3
    const int ty  = tid >> 4;          // node group: nodes ty*4 .. ty*4+3
    const int n0  = blockIdx.x * TM;

    for (int i = tid; i < F * F; i += 256) sW[i] = W_in[i];
    if (tid < F) {
        sWu[tid] = W_edge[tid];
        sWv[tid] = W_edge[F + tid];
        sW0[tid] = W_out[tid * NCLS + 0];
        sW1[tid] = W_out[tid * NCLS + 1];
    }

    #pragma unroll
    for (int p = 0; p < 4; ++p) {
        const int node = p * 16 + ty;
        const int k4   = tx * 4;
        const int n    = n0 + node;
        float4 v = make_float4(0.f, 0.f, 0.f, 0.f);
        if (n < N_NODES) v = *(const float4*)&feat[(size_t)n * F + k4];
        sT[(k4 + 0) * STRIDE + node] = v.x;
        sT[(k4 + 1) * STRIDE + node] = v.y;
        sT[(k4 + 2) * STRIDE + node] = v.z;
        sT[(k4 + 3) * STRIDE + node] = v.w;
    }
    __syncthreads();

    const float4 bb = *(const float4*)&b_in[tx * 4];
    float acc[4][4];
    #pragma unroll
    for (int i = 0; i < 4; ++i) {
        acc[i][0] = bb.x; acc[i][1] = bb.y; acc[i][2] = bb.z; acc[i][3] = bb.w;
    }

    #pragma unroll 4
    for (int k = 0; k < F; ++k) {
        const float4 a = *(const float4*)&sT[k * STRIDE + ty * 4];
        const float4 b = *(const float4*)&sW[k * F + tx * 4];
        const float av_[4] = {a.x, a.y, a.z, a.w};
        const float bv_[4] = {b.x, b.y, b.z, b.w};
        #pragma unroll
        for (int i = 0; i < 4; ++i)
            #pragma unroll
            for (int j = 0; j < 4; ++j)
                acc[i][j] += av_[i] * bv_[j];
    }

    const float wu[4] = { sWu[tx*4+0], sWu[tx*4+1], sWu[tx*4+2], sWu[tx*4+3] };
    const float wv[4] = { sWv[tx*4+0], sWv[tx*4+1], sWv[tx*4+2], sWv[tx*4+3] };
    const float w0[4] = { sW0[tx*4+0], sW0[tx*4+1], sW0[tx*4+2], sW0[tx*4+3] };
    const float w1[4] = { sW1[tx*4+0], sW1[tx*4+1], sW1[tx*4+2], sW1[tx*4+3] };

    #pragma unroll
    for (int i = 0; i < 4; ++i) {
        const int n = n0 + ty * 4 + i;
        float pa = 0.f, pb = 0.f, p0 = 0.f, p1 = 0.f;
        #pragma unroll
        for (int j = 0; j < 4; ++j) {
            pa += acc[i][j] * wu[j];
            pb += acc[i][j] * wv[j];
            p0 += acc[i][j] * w0[j];
            p1 += acc[i][j] * w1[j];
        }
        #pragma unroll
        for (int off = 8; off > 0; off >>= 1) {
            pa += __shfl_xor(pa, off);
            pb += __shfl_xor(pb, off);
            p0 += __shfl_xor(p0, off);
            p1 += __shfl_xor(p1, off);
        }
        if (n < N_NODES && tx == 0)
            nodeT[n] = make_float4(pa, p0, p1, pb);
    }
}

// ---------------------------------------------------------------------------
// K2: exclusive scan of NB bucket counts (single block, Hillis-Steele).
// ---------------------------------------------------------------------------
__global__ __launch_bounds__(1024) void bucket_scan_kernel(
    const int* __restrict__ bucket_cnt,
    int* __restrict__ bucket_base,
    int* __restrict__ bucket_cursor)
{
    __shared__ int s[1024];
    const int t = threadIdx.x;
    const int v = (t < NB) ? bucket_cnt[t] : 0;
    s[t] = v;
    __syncthreads();
    for (int off = 1; off < 1024; off <<= 1) {
        int tv = (t >= off) ? s[t - off] : 0;
        __syncthreads();
        s[t] += tv;
        __syncthreads();
    }
    if (t < NB) {
        const int excl = s[t] - v;
        bucket_base[t]   = excl;
        bucket_cursor[t] = excl;
    }
    if (t == 0) bucket_base[NB] = N_EDGES;
}

// ---------------------------------------------------------------------------
// K3: scatter per-edge message records into dst-bucket-contiguous runs.
// Record: (dst&127, A[src]+b_edge, hw0[src], hw1[src]) as int4 (16 B aligned).
// Zero global atomics on the data path (one cursor atomic per (block,bucket)).
// ---------------------------------------------------------------------------
__global__ __launch_bounds__(256) void scatter_msg_kernel(
    const int* __restrict__ src, const int* __restrict__ dst,
    const float4* __restrict__ nodeT,
    const float* __restrict__ b_edge,
    int* __restrict__ bucket_cursor,
    int4* __restrict__ ework)
{
    __shared__ int hist[NB];
    __shared__ int base[NB];
    for (int i = threadIdx.x; i < NB; i += 256) hist[i] = 0;
    __syncthreads();

    const int beg = blockIdx.x * EPB;
    const int end = beg + EPB;
    for (int e = beg + threadIdx.x; e < end; e += 256)
        atomicAdd(&hist[dst[e] >> BW_LOG], 1);
    __syncthreads();

    for (int b = threadIdx.x; b < NB; b += 256) {
        if (hist[b]) base[b] = atomicAdd(&bucket_cursor[b], hist[b]);
        hist[b] = 0;   // reuse as rank counter
    }
    __syncthreads();

    const float be = b_edge[0];
    for (int e = beg + threadIdx.x; e < end; e += 256) {
        const int d = dst[e];
        const int b = d >> BW_LOG;
        const int r = atomicAdd(&hist[b], 1);
        const float4 t = nodeT[src[e]];          // (A, hw0, hw1, B) — L2 hit
        ework[base[b] + r] = make_int4(d & (BW - 1),
                                       __float_as_int(t.x + be),
                                       __float_as_int(t.y),
                                       __float_as_int(t.z));
    }
}

// ---------------------------------------------------------------------------
// K4: one block per bucket — LDS-atomic aggregation over 128 nodes + fused
// finalize. No global atomics, writes only the 800 KB output.
// ---------------------------------------------------------------------------
__global__ __launch_bounds__(256) void bucket_agg_kernel(
    const int4* __restrict__ ework,
    const int* __restrict__ bucket_base,
    const float4* __restrict__ nodeT,
    const float* __restrict__ b_out,
    float2* __restrict__ out)
{
    __shared__ float sB[BW];
    __shared__ float sm0[BW];
    __shared__ float sm1[BW];
    __shared__ int   sdeg[BW];

    const int b   = blockIdx.x;
    const int tid = threadIdx.x;

    float f0 = 0.f, f1 = 0.f;
    if (tid < BW) {
        const int n = b * BW + tid;
        float4 t = make_float4(0.f, 0.f, 0.f, 0.f);
        if (n < N_NODES) t = nodeT[n];
        sB[tid] = t.w; f0 = t.y; f1 = t.z;
        sm0[tid] = 0.f; sm1[tid] = 0.f; sdeg[tid] = 0;
    }
    __syncthreads();

    const int beg = bucket_base[b];
    const int end = bucket_base[b + 1];
    for (int i = beg + tid; i < end; i += 256) {
        const int4 e = ework[i];
        const float x = __int_as_float(e.y) + sB[e.x];
        const float w = 1.0f / (1.0f + __expf(-x));
        atomicAdd(&sm0[e.x], w * __int_as_float(e.z));
        atomicAdd(&sm1[e.x], w * __int_as_float(e.w));
        atomicAdd(&sdeg[e.x], 1);
    }
    __syncthreads();

    if (tid < BW) {
        const int n = b * BW + tid;
        if (n < N_NODES) {
            const float o0 = (sdeg[tid] > 0 ? sm0[tid] : f0) + b_out[0];
            const float o1 = (sdeg[tid] > 0 ? sm1[tid] : f1) + b_out[1];
            out[n] = make_float2(o0, o1);
        }
    }
}

// ---------------------------------------------------------------------------
extern "C" void kernel_launch(void* const* d_in, const int* in_sizes, int n_in,
                              void* d_out, int out_size, void* d_ws, size_t ws_size,
                              hipStream_t stream) {
    const float* feat   = (const float*)d_in[0];
    const int*   src    = (const int*)d_in[1];
    const int*   dst    = (const int*)d_in[2];
    const float* W_in   = (const float*)d_in[3];
    const float* b_in   = (const float*)d_in[4];
    const float* W_edge = (const float*)d_in[5];
    const float* b_edge = (const float*)d_in[6];
    const float* W_out  = (const float*)d_in[7];
    const float* b_out  = (const float*)d_in[8];
    float2* out = (float2*)d_out;

    // workspace layout (16B-aligned blocks first)
    float4* nodeT         = (float4*)d_ws;                   // N float4 (1.6 MB)
    int4*   ework         = (int4*)(nodeT + N_NODES);        // E int4  (25.6 MB)
    int*    bucket_cnt    = (int*)(ework + N_EDGES);         // NB
    int*    bucket_base   = bucket_cnt + NB;                 // NB+1
    int*    bucket_cursor = bucket_base + NB + 1;            // NB

    hipMemsetAsync(bucket_cnt, 0, NB * sizeof(int), stream);

    mlp_hist_kernel<<<BLOCKS_MLP + 256, 256, 0, stream>>>(
        feat, W_in, b_in, W_edge, W_out, dst, nodeT, bucket_cnt);
    bucket_scan_kernel<<<1, 1024, 0, stream>>>(bucket_cnt, bucket_base, bucket_cursor);
    scatter_msg_kernel<<<256, 256, 0, stream>>>(src, dst, nodeT, b_edge,
                                                bucket_cursor, ework);
    bucket_agg_kernel<<<NB, 256, 0, stream>>>(ework, bucket_base, nodeT, b_out, out);
}